// Round 1
// baseline (159.292 us; speedup 1.0000x reference)
//
#include <hip/hip_runtime.h>
#include <hip/hip_bf16.h>
#include <math.h>

// Problem constants (from reference): B=2048, I=512, O=512
#define B_DIM 2048
#define I_DIM 512
#define O_DIM 512

// Each main-kernel thread handles R consecutive b-rows for one o column.
// R=16: 256 blocks total (1/CU), 16 independent product chains per thread
// (ILP), and ab-table L2 traffic = 256 blocks * 1MB = 256MB (~19 TB/s,
// under the 34.5 TB/s L2 ceiling).
constexpr int R_ROWS = 16;

// ---------------------------------------------------------------------------
// Kernel 1: precompute the affine factor table.
//   factor[b,i,o] = 1 - w*(x + s - 2xs) = a[i,o] + bcoef[i,o]*x[b,i]
//   a = 1 - w*s ; bcoef = w*(2s - 1)
// Layout: float4 per (i-pair, o): (a_{2k}, b_{2k}, a_{2k+1}, b_{2k+1})
// stored at ab4[k*O_DIM + o]  (k = i/2). Coalesced read in main kernel.
// ---------------------------------------------------------------------------
__global__ __launch_bounds__(256) void precompute_ab(
    const float* __restrict__ w_logits,
    const float* __restrict__ s_logits,
    float4* __restrict__ ab4)
{
    int t = blockIdx.x * 256 + threadIdx.x;       // 0 .. 131071
    int o  = t & (O_DIM - 1);
    int k  = t >> 9;                              // i-pair index, 0..255
    int i0 = 2 * k;

    float zw0 = w_logits[(i0 + 0) * O_DIM + o];
    float zs0 = s_logits[(i0 + 0) * O_DIM + o];
    float zw1 = w_logits[(i0 + 1) * O_DIM + o];
    float zs1 = s_logits[(i0 + 1) * O_DIM + o];

    // Full-precision sigmoid (libm expf): error budget matters since the
    // product chain multiplies 512 factors.
    float w0 = 1.0f / (1.0f + expf(-zw0));
    float s0 = 1.0f / (1.0f + expf(-zs0));
    float w1 = 1.0f / (1.0f + expf(-zw1));
    float s1 = 1.0f / (1.0f + expf(-zs1));

    float4 v;
    v.x = fmaf(-w0, s0, 1.0f);        // a0
    v.y = w0 * (2.0f * s0 - 1.0f);    // b0
    v.z = fmaf(-w1, s1, 1.0f);        // a1
    v.w = w1 * (2.0f * s1 - 1.0f);    // b1
    ab4[k * O_DIM + o] = v;
}

// ---------------------------------------------------------------------------
// Kernel 2: main product.
//   out[b,o] = prod_i (a[i,o] + b[i,o]*x[b,i])
// Thread: o = blockIdx.x*256 + tid (lane-varying -> coalesced ab loads),
//         b in [b0, b0+R) (block-uniform -> scalar s_load of x rows).
// ---------------------------------------------------------------------------
__global__ __launch_bounds__(256) void fuzzy_main(
    const float* __restrict__ x,
    const float4* __restrict__ ab4,
    float* __restrict__ out)
{
    const int o  = blockIdx.x * 256 + threadIdx.x;
    const int b0 = blockIdx.y * R_ROWS;
    const float* xp = x + b0 * I_DIM;

    float acc[R_ROWS];
#pragma unroll
    for (int r = 0; r < R_ROWS; ++r) acc[r] = 1.0f;

    // Software-pipelined: prefetch next chunk's ab (2 float4 = 4 i values)
    // while computing current chunk. Only ~1 wave/SIMD, so explicit lookahead
    // helps hide the ~200cyc L2 latency.
    float4 p0 = ab4[0 * O_DIM + o];
    float4 p1 = ab4[1 * O_DIM + o];

    for (int k = 0; k < I_DIM / 2; k += 2) {      // k = i-pair index, 4 i/iter
        float4 c0 = p0;
        float4 c1 = p1;
        int kn = (k + 2) & (I_DIM / 2 - 1);       // wraps to 0 on last iter (harmless)
        p0 = ab4[(kn + 0) * O_DIM + o];
        p1 = ab4[(kn + 1) * O_DIM + o];

        const int i = 2 * k;
#pragma unroll
        for (int r = 0; r < R_ROWS; ++r) {
            // Wave-uniform address -> scalar loads (s_load_dwordx4).
            float x0 = xp[r * I_DIM + i + 0];
            float x1 = xp[r * I_DIM + i + 1];
            float x2 = xp[r * I_DIM + i + 2];
            float x3 = xp[r * I_DIM + i + 3];
            float f0 = fmaf(c0.y, x0, c0.x);
            float f1 = fmaf(c0.w, x1, c0.z);
            float f2 = fmaf(c1.y, x2, c1.x);
            float f3 = fmaf(c1.w, x3, c1.z);
            // Tree-shaped to keep the serial dependence short; 16 independent
            // chains across r give the ILP.
            acc[r] = (acc[r] * (f0 * f1)) * (f2 * f3);
        }
    }

#pragma unroll
    for (int r = 0; r < R_ROWS; ++r)
        out[(b0 + r) * O_DIM + o] = acc[r];
}

extern "C" void kernel_launch(void* const* d_in, const int* in_sizes, int n_in,
                              void* d_out, int out_size, void* d_ws, size_t ws_size,
                              hipStream_t stream) {
    const float* x        = (const float*)d_in[0];   // (B, I) fp32
    const float* w_logits = (const float*)d_in[1];   // (I, O) fp32
    const float* s_logits = (const float*)d_in[2];   // (I, O) fp32
    float* out = (float*)d_out;                      // (B, O) fp32
    float4* ab4 = (float4*)d_ws;                     // needs I*O*8 = 2 MB

    // Precompute affine factor table: 131072 threads.
    precompute_ab<<<dim3((I_DIM / 2) * O_DIM / 256), dim3(256), 0, stream>>>(
        w_logits, s_logits, ab4);

    // Main: grid (O/256, B/R) = (2, 128) = 256 blocks of 256 threads.
    fuzzy_main<<<dim3(O_DIM / 256, B_DIM / R_ROWS), dim3(256), 0, stream>>>(
        x, ab4, out);
}

// Round 2
// 100.193 us; speedup vs baseline: 1.5899x; 1.5899x over previous
//
#include <hip/hip_runtime.h>
#include <hip/hip_bf16.h>
#include <math.h>

// Problem constants (from reference): B=2048, I=512, O=512
#define B_DIM 2048
#define I_DIM 512
#define O_DIM 512

constexpr int R_ROWS  = 16;              // b-rows per block
constexpr int W_CHUNK = 4;               // i-chunks (threadIdx.y)
constexpr int CHUNK   = I_DIM / W_CHUNK; // 128 i per chunk
constexpr int KP      = CHUNK / 2;       // 64 i-pair rows per chunk

// ---------------------------------------------------------------------------
// Kernel 1: precompute the affine factor table.
//   factor[b,i,o] = 1 - w*(x + s - 2xs) = a[i,o] + bcoef[i,o]*x[b,i]
//   a = 1 - w*s ; bcoef = w*(2s - 1)
// Layout: float4 per (i-pair, o): (a_{2k}, b_{2k}, a_{2k+1}, b_{2k+1})
// stored at ab4[k*O_DIM + o]  (k = i/2). Coalesced read in main kernel.
// ---------------------------------------------------------------------------
__global__ __launch_bounds__(256) void precompute_ab(
    const float* __restrict__ w_logits,
    const float* __restrict__ s_logits,
    float4* __restrict__ ab4)
{
    int t = blockIdx.x * 256 + threadIdx.x;       // 0 .. 131071
    int o  = t & (O_DIM - 1);
    int k  = t >> 9;                              // i-pair index, 0..255
    int i0 = 2 * k;

    float zw0 = w_logits[(i0 + 0) * O_DIM + o];
    float zs0 = s_logits[(i0 + 0) * O_DIM + o];
    float zw1 = w_logits[(i0 + 1) * O_DIM + o];
    float zs1 = s_logits[(i0 + 1) * O_DIM + o];

    float w0 = 1.0f / (1.0f + expf(-zw0));
    float s0 = 1.0f / (1.0f + expf(-zs0));
    float w1 = 1.0f / (1.0f + expf(-zw1));
    float s1 = 1.0f / (1.0f + expf(-zs1));

    float4 v;
    v.x = fmaf(-w0, s0, 1.0f);        // a0
    v.y = w0 * (2.0f * s0 - 1.0f);    // b0
    v.z = fmaf(-w1, s1, 1.0f);        // a1
    v.w = w1 * (2.0f * s1 - 1.0f);    // b1
    ab4[k * O_DIM + o] = v;
}

// ---------------------------------------------------------------------------
// Kernel 2: main product, i-split across threadIdx.y for occupancy.
//   Block (256, 4): lane dim = o (coalesced ab), y = i-chunk (disjoint ab
//   quarters -> no redundant L2 traffic). 16 waves/block, 256 blocks ->
//   4 waves/SIMD so s_load/vmem latency overlaps across waves.
//   Partial products combined through a 32KB LDS buffer in two 8-row passes.
// ---------------------------------------------------------------------------
__global__ __launch_bounds__(1024, 4) void fuzzy_main(
    const float* __restrict__ x,
    const float4* __restrict__ ab4,
    float* __restrict__ out)
{
    __shared__ float part[W_CHUNK][8][256];   // 32 KB

    const int o_l = threadIdx.x;              // 0..255
    const int o   = blockIdx.x * 256 + o_l;
    // Pin y wave-uniform so x addresses are provably uniform -> scalar loads.
    const int y   = __builtin_amdgcn_readfirstlane((int)threadIdx.y); // 0..3
    const int b0  = blockIdx.y * R_ROWS;

    const float*  xp  = x + b0 * I_DIM + y * CHUNK;
    const float4* abp = ab4 + (size_t)(y * KP) * O_DIM + o;

    float acc[R_ROWS];
#pragma unroll
    for (int r = 0; r < R_ROWS; ++r) acc[r] = 1.0f;

    // Prefetch one iteration (2 float4 = 4 i values) ahead.
    float4 p0 = abp[0];
    float4 p1 = abp[O_DIM];

    for (int k = 0; k < KP; k += 2) {         // 32 iterations, 4 i per iter
        float4 c0 = p0;
        float4 c1 = p1;
        // k+2 overreads into the next chunk's rows for y<3; for y=3 the max
        // index is (192 + 33) = 225 < 256 total k-rows -> always in bounds.
        p0 = abp[(size_t)(k + 2) * O_DIM];
        p1 = abp[(size_t)(k + 3) * O_DIM];

        const int i = 2 * k;
#pragma unroll
        for (int r = 0; r < R_ROWS; ++r) {
            // Wave-uniform addresses -> scalar pipe (s_load_dwordx4).
            float x0 = xp[r * I_DIM + i + 0];
            float x1 = xp[r * I_DIM + i + 1];
            float x2 = xp[r * I_DIM + i + 2];
            float x3 = xp[r * I_DIM + i + 3];
            float f0 = fmaf(c0.y, x0, c0.x);
            float f1 = fmaf(c0.w, x1, c0.z);
            float f2 = fmaf(c1.y, x2, c1.x);
            float f3 = fmaf(c1.w, x3, c1.z);
            acc[r] = (acc[r] * (f0 * f1)) * (f2 * f3);
        }
    }

    // Combine the 4 i-chunk partials per (row, o) via LDS, 8 rows per pass.
#pragma unroll
    for (int half = 0; half < 2; ++half) {
        if (half) __syncthreads();            // protect LDS reuse
#pragma unroll
        for (int rr = 0; rr < 8; ++rr)
            part[y][rr][o_l] = acc[half * 8 + rr];
        __syncthreads();
        // 8 rows / 4 y-groups -> 2 rows per thread; stride-1 in o -> coalesced.
#pragma unroll
        for (int rr2 = 0; rr2 < 2; ++rr2) {
            int r8 = y * 2 + rr2;
            float v = part[0][r8][o_l] * part[1][r8][o_l]
                    * part[2][r8][o_l] * part[3][r8][o_l];
            out[(size_t)(b0 + half * 8 + r8) * O_DIM + o] = v;
        }
    }
}

extern "C" void kernel_launch(void* const* d_in, const int* in_sizes, int n_in,
                              void* d_out, int out_size, void* d_ws, size_t ws_size,
                              hipStream_t stream) {
    const float* x        = (const float*)d_in[0];   // (B, I) fp32
    const float* w_logits = (const float*)d_in[1];   // (I, O) fp32
    const float* s_logits = (const float*)d_in[2];   // (I, O) fp32
    float* out = (float*)d_out;                      // (B, O) fp32
    float4* ab4 = (float4*)d_ws;                     // needs I*O*8 = 2 MB

    precompute_ab<<<dim3((I_DIM / 2) * O_DIM / 256), dim3(256), 0, stream>>>(
        w_logits, s_logits, ab4);

    // Grid (O/256, B/R) = (2, 128) = 256 blocks of (256,4)=1024 threads.
    fuzzy_main<<<dim3(O_DIM / 256, B_DIM / R_ROWS), dim3(256, W_CHUNK), 0, stream>>>(
        x, ab4, out);
}

// Round 3
// 94.398 us; speedup vs baseline: 1.6875x; 1.0614x over previous
//
#include <hip/hip_runtime.h>
#include <hip/hip_bf16.h>
#include <math.h>

// Problem constants (from reference): B=2048, I=512, O=512
#define B_DIM 2048
#define I_DIM 512
#define O_DIM 512

constexpr int R_ROWS  = 8;               // b-rows per block (R2: 16 -> 8 for 2 blocks/CU)
constexpr int W_CHUNK = 4;               // i-chunks (threadIdx.y)
constexpr int CHUNK   = I_DIM / W_CHUNK; // 128 i per chunk
constexpr int KP      = CHUNK / 2;       // 64 i-pair rows per chunk
constexpr int KROWS   = I_DIM / 2;       // 256 total i-pair rows

// ---------------------------------------------------------------------------
// Kernel 1: precompute the affine factor table.
//   factor[b,i,o] = 1 - w*(x + s - 2xs) = a[i,o] + bcoef[i,o]*x[b,i]
//   a = 1 - w*s ; bcoef = w*(2s - 1)
// Layout (pk-friendly): float4 per (i-pair, o) = (a0, a1, b0, b1) at
// ab4[k*O_DIM + o] (k = i/2). The (a0,a1) and (b0,b1) adjacent pairs let the
// SLP vectorizer form v_pk_fma_f32 in the main kernel.
// ---------------------------------------------------------------------------
__global__ __launch_bounds__(256) void precompute_ab(
    const float* __restrict__ w_logits,
    const float* __restrict__ s_logits,
    float4* __restrict__ ab4)
{
    int t = blockIdx.x * 256 + threadIdx.x;       // 0 .. 131071
    int o  = t & (O_DIM - 1);
    int k  = t >> 9;                              // i-pair index, 0..255
    int i0 = 2 * k;

    float zw0 = w_logits[(i0 + 0) * O_DIM + o];
    float zs0 = s_logits[(i0 + 0) * O_DIM + o];
    float zw1 = w_logits[(i0 + 1) * O_DIM + o];
    float zs1 = s_logits[(i0 + 1) * O_DIM + o];

    float w0 = 1.0f / (1.0f + expf(-zw0));
    float s0 = 1.0f / (1.0f + expf(-zs0));
    float w1 = 1.0f / (1.0f + expf(-zw1));
    float s1 = 1.0f / (1.0f + expf(-zs1));

    float4 v;
    v.x = fmaf(-w0, s0, 1.0f);        // a0
    v.y = fmaf(-w1, s1, 1.0f);        // a1
    v.z = w0 * (2.0f * s0 - 1.0f);    // b0
    v.w = w1 * (2.0f * s1 - 1.0f);    // b1
    ab4[k * O_DIM + o] = v;
}

// ---------------------------------------------------------------------------
// Kernel 2: main product, i-split across threadIdx.y.
//   Block (256, 4): lane dim = o (coalesced ab), y = i-chunk (disjoint ab
//   quarters). Grid (2, 256) = 512 blocks -> 2 blocks/CU -> 32 waves/CU
//   (100% theoretical occupancy; R2's 256-block grid capped us at 50%).
//   Inner math arranged in adjacent pairs to invite v_pk_fma_f32/v_pk_mul_f32.
//   Partial products combined via one 32KB LDS pass.
// ---------------------------------------------------------------------------
__global__ __launch_bounds__(1024, 8) void fuzzy_main(
    const float* __restrict__ x,
    const float4* __restrict__ ab4,
    float* __restrict__ out)
{
    __shared__ float part[W_CHUNK][R_ROWS][256];   // 4*8*256*4 = 32 KB

    const int o_l = threadIdx.x;              // 0..255
    const int o   = blockIdx.x * 256 + o_l;
    // Pin y wave-uniform so x addresses are provably uniform -> scalar loads.
    const int y   = __builtin_amdgcn_readfirstlane((int)threadIdx.y); // 0..3
    const int b0  = blockIdx.y * R_ROWS;

    const float*  xp  = x + b0 * I_DIM + y * CHUNK;
    const int     kbase = y * KP;             // this chunk's first ab row

    // Two independent partial products per row (pk lanes); combined at end.
    float acc0[R_ROWS], acc1[R_ROWS];
#pragma unroll
    for (int r = 0; r < R_ROWS; ++r) { acc0[r] = 1.0f; acc1[r] = 1.0f; }

    // Prefetch one iteration (2 float4 = 4 i values) ahead.
    float4 p0 = ab4[(size_t)(kbase + 0) * O_DIM + o];
    float4 p1 = ab4[(size_t)(kbase + 1) * O_DIM + o];

    for (int k = 0; k < KP; k += 2) {         // 32 iterations, 4 i per iter
        float4 c0 = p0;                       // (a0,a1,b0,b1) for i=2k,2k+1
        float4 c1 = p1;                       // (a0,a1,b0,b1) for i=2k+2,2k+3
        // Wrap the prefetch row into [0,256): last-iteration loads are dead
        // but must stay in bounds (R2 read up to row 257 of 256 -> OOB).
        int kn = (kbase + k + 2) & (KROWS - 1);
        p0 = ab4[(size_t)(kn + 0) * O_DIM + o];
        p1 = ab4[(size_t)(kn + 1) * O_DIM + o];

        const int i = 2 * k;
#pragma unroll
        for (int r = 0; r < R_ROWS; ++r) {
            // Wave-uniform addresses -> scalar pipe (one s_load_dwordx4).
            const float* xr = xp + r * I_DIM + i;
            float x0 = xr[0];
            float x1 = xr[1];
            float x2 = xr[2];
            float x3 = xr[3];
            // Adjacent pairs (f0,f1) and (f2,f3): pk_fma candidates.
            float f0 = fmaf(c0.z, x0, c0.x);
            float f1 = fmaf(c0.w, x1, c0.y);
            float f2 = fmaf(c1.z, x2, c1.x);
            float f3 = fmaf(c1.w, x3, c1.y);
            // (h0,h1) and the acc update: pk_mul candidates.
            float h0 = f0 * f2;
            float h1 = f1 * f3;
            acc0[r] *= h0;
            acc1[r] *= h1;
        }
    }

    // Combine the 4 i-chunk partials per (row, o) via LDS, single pass.
#pragma unroll
    for (int r = 0; r < R_ROWS; ++r)
        part[y][r][o_l] = acc0[r] * acc1[r];
    __syncthreads();
    // 8 rows / 4 y-groups -> 2 rows per thread; stride-1 in o -> coalesced.
#pragma unroll
    for (int rr = 0; rr < 2; ++rr) {
        int r8 = y * 2 + rr;
        float v = part[0][r8][o_l] * part[1][r8][o_l]
                * part[2][r8][o_l] * part[3][r8][o_l];
        out[(size_t)(b0 + r8) * O_DIM + o] = v;
    }
}

extern "C" void kernel_launch(void* const* d_in, const int* in_sizes, int n_in,
                              void* d_out, int out_size, void* d_ws, size_t ws_size,
                              hipStream_t stream) {
    const float* x        = (const float*)d_in[0];   // (B, I) fp32
    const float* w_logits = (const float*)d_in[1];   // (I, O) fp32
    const float* s_logits = (const float*)d_in[2];   // (I, O) fp32
    float* out = (float*)d_out;                      // (B, O) fp32
    float4* ab4 = (float4*)d_ws;                     // needs I*O*8 = 2 MB

    precompute_ab<<<dim3((I_DIM / 2) * O_DIM / 256), dim3(256), 0, stream>>>(
        w_logits, s_logits, ab4);

    // Grid (O/256, B/R) = (2, 256) = 512 blocks of (256,4)=1024 threads.
    fuzzy_main<<<dim3(O_DIM / 256, B_DIM / R_ROWS), dim3(256, W_CHUNK), 0, stream>>>(
        x, ab4, out);
}